// Round 2
// baseline (106.580 us; speedup 1.0000x reference)
//
#include <hip/hip_runtime.h>

// SlotContrastiveLoss B=32768, K=8, D=256 fp32.
// MFMA restructure: one 16x16x32_bf16 tile = 2 batches (rows 0-7 = batch b0
// A-rows, 8-15 = b1; cols likewise for S). 8 MFMAs over K=256. C-layout:
// col = lane&15, row = (lane>>4)*4 + reg. Norms via fp32 ssq + 2 shfl fold;
// ns[col] lands in-lane, na[row] via 4 bpermutes. LSE over 8-lane col groups.
// Cross-batch quadrants masked. Deterministic 2-stage reduction, no atomics.

typedef __attribute__((ext_vector_type(8))) short bf16x8;
typedef __attribute__((ext_vector_type(4))) float f32x4;

__device__ inline short f2bf(float f) {
  union { float f; unsigned u; } v; v.f = f;
  unsigned u = v.u;
  u += 0x7fffu + ((u >> 16) & 1u);   // round-to-nearest-even
  return (short)(u >> 16);
}

extern "C" __global__ __launch_bounds__(256)
void slot_ce_mfma(const float* __restrict__ ds, const float* __restrict__ ss,
                  const float* __restrict__ tptr, float* __restrict__ ws,
                  int ntiles) {
  const int lane = threadIdx.x & 63;
  const int wid  = (blockIdx.x * (blockDim.x >> 6)) + (threadIdx.x >> 6);
  const int m = lane & 15;            // fragment row / C col
  const int h = lane >> 4;            // k-slice group / C row group
  const float inv_t = 1.0f / tptr[0];

  float loss = 0.0f;

  if (wid < ntiles) {
    // tile = 2 consecutive batches -> 16 rows of 256 floats, contiguous
    const float4* pa = (const float4*)(ds + (size_t)wid * 4096);
    const float4* pb = (const float4*)(ss + (size_t)wid * 4096);
    const int base = m * 64 + h * 2;  // float4 index: row m, k-offset h*8

    f32x4 acc = {0.f, 0.f, 0.f, 0.f};
    float ssqA = 0.f, ssqS = 0.f;

#pragma unroll
    for (int kb = 0; kb < 8; ++kb) {
      const int idx = base + kb * 8;
      float4 a0 = pa[idx], a1 = pa[idx + 1];
      float4 s0 = pb[idx], s1 = pb[idx + 1];

      ssqA += a0.x*a0.x + a0.y*a0.y + a0.z*a0.z + a0.w*a0.w
            + a1.x*a1.x + a1.y*a1.y + a1.z*a1.z + a1.w*a1.w;
      ssqS += s0.x*s0.x + s0.y*s0.y + s0.z*s0.z + s0.w*s0.w
            + s1.x*s1.x + s1.y*s1.y + s1.z*s1.z + s1.w*s1.w;

      bf16x8 af = { f2bf(a0.x), f2bf(a0.y), f2bf(a0.z), f2bf(a0.w),
                    f2bf(a1.x), f2bf(a1.y), f2bf(a1.z), f2bf(a1.w) };
      bf16x8 sf = { f2bf(s0.x), f2bf(s0.y), f2bf(s0.z), f2bf(s0.w),
                    f2bf(s1.x), f2bf(s1.y), f2bf(s1.z), f2bf(s1.w) };
      acc = __builtin_amdgcn_mfma_f32_16x16x32_bf16(af, sf, acc, 0, 0, 0);
    }

    // fold ssq over the 4 lanes sharing row m (bits 4,5) -> full row norms^2
    ssqA += __shfl_xor(ssqA, 16, 64);
    ssqA += __shfl_xor(ssqA, 32, 64);
    ssqS += __shfl_xor(ssqS, 16, 64);
    ssqS += __shfl_xor(ssqS, 32, 64);
    // lane now holds na2 = ||A row m||^2, ns2 = ||S row m||^2; C col = m,
    // so ns2 is already the right col norm. Gather na2 for rows 4h+r:
    float na0 = __shfl(ssqA, h * 4 + 0, 64);
    float na1 = __shfl(ssqA, h * 4 + 1, 64);
    float na2 = __shfl(ssqA, h * 4 + 2, 64);
    float na3 = __shfl(ssqA, h * 4 + 3, 64);

    float lg0 = acc[0] * rsqrtf(na0 * ssqS) * inv_t;
    float lg1 = acc[1] * rsqrtf(na1 * ssqS) * inv_t;
    float lg2 = acc[2] * rsqrtf(na2 * ssqS) * inv_t;
    float lg3 = acc[3] * rsqrtf(na3 * ssqS) * inv_t;

    // LSE across the 8 cols of this batch (lanes differing in bits 0..2)
    float c = 0.0f;
#pragma unroll
    for (int r = 0; r < 4; ++r) {
      float lg = r == 0 ? lg0 : r == 1 ? lg1 : r == 2 ? lg2 : lg3;
      float mx = lg;
      mx = fmaxf(mx, __shfl_xor(mx, 1, 64));
      mx = fmaxf(mx, __shfl_xor(mx, 2, 64));
      mx = fmaxf(mx, __shfl_xor(mx, 4, 64));
      float e = __expf(lg - mx);
      e += __shfl_xor(e, 1, 64);
      e += __shfl_xor(e, 2, 64);
      e += __shfl_xor(e, 4, 64);
      float lse = mx + __logf(e);
      c += lse * 0.125f;                       // lse replicated over 8 col-lanes
      if (4 * h + r == m) c -= lg;             // diagonal (positive logit)
    }
    // valid lanes: same-batch quadrants of the 16x16 tile
    if ((m >= 8) == (h >= 2)) loss = c;
  }

  // deterministic wave -> block reduction
#pragma unroll
  for (int o = 32; o >= 1; o >>= 1) loss += __shfl_xor(loss, o, 64);
  __shared__ float red[4];
  if (lane == 0) red[threadIdx.x >> 6] = loss;
  __syncthreads();
  if (threadIdx.x == 0)
    ws[blockIdx.x] = (red[0] + red[1]) + (red[2] + red[3]);
}

extern "C" __global__ __launch_bounds__(256)
void slot_ce_finish(const float* __restrict__ ws, float* __restrict__ out,
                    int nparts, float scale) {
  __shared__ float red[256];
  float s = 0.0f;
  for (int i = threadIdx.x; i < nparts; i += 256) s += ws[i];
  red[threadIdx.x] = s;
  __syncthreads();
  for (int o = 128; o >= 1; o >>= 1) {
    if ((int)threadIdx.x < o) red[threadIdx.x] += red[threadIdx.x + o];
    __syncthreads();
  }
  if (threadIdx.x == 0) out[0] = red[0] * scale;
}

extern "C" void kernel_launch(void* const* d_in, const int* in_sizes, int n_in,
                              void* d_out, int out_size, void* d_ws, size_t ws_size,
                              hipStream_t stream) {
  const float* ds   = (const float*)d_in[0];
  const float* ss   = (const float*)d_in[1];
  const float* tptr = (const float*)d_in[3];   // d_in[2] = labels (unused)
  float* out = (float*)d_out;
  float* ws  = (float*)d_ws;

  const int B      = in_sizes[0] / (8 * 256);  // 32768
  const int ntiles = B / 2;                    // 2 batches per wave-tile
  const int blocks = (ntiles + 3) / 4;         // 4 waves per block

  slot_ce_mfma<<<blocks, 256, 0, stream>>>(ds, ss, tptr, ws, ntiles);
  const float scale = 1.0f / (8.0f * (float)B);
  slot_ce_finish<<<1, 256, 0, stream>>>(ws, out, blocks, scale);
}

// Round 3
// 106.472 us; speedup vs baseline: 1.0010x; 1.0010x over previous
//
#include <hip/hip_runtime.h>
#include <hip/hip_bf16.h>

// SlotContrastiveLoss B=32768, K=8, D=256 fp32.
// One wave = one 16x16x32_bf16 tile = 2 batches. R3 change: hoist all 32
// dwordx4 loads (16KB/tensor tile) into registers up front for max per-wave
// MLP, then convert+MFMA against landed data. C-layout col=lane&15,
// row=(lane>>4)*4+reg (validated absmax 0.0 in R2). cvt via
// __float22bfloat162_rn -> v_cvt_pk_bf16_f32. Deterministic reduction.

typedef __attribute__((ext_vector_type(8))) short bf16x8;
typedef __attribute__((ext_vector_type(4))) float f32x4;

union BFPack { bf16x8 v; __hip_bfloat162 h[4]; };

__device__ inline bf16x8 pack8(const float4& lo, const float4& hi) {
  BFPack u;
  u.h[0] = __float22bfloat162_rn(make_float2(lo.x, lo.y));
  u.h[1] = __float22bfloat162_rn(make_float2(lo.z, lo.w));
  u.h[2] = __float22bfloat162_rn(make_float2(hi.x, hi.y));
  u.h[3] = __float22bfloat162_rn(make_float2(hi.z, hi.w));
  return u.v;
}

extern "C" __global__ __launch_bounds__(256, 2)
void slot_ce_mfma(const float* __restrict__ ds, const float* __restrict__ ss,
                  const float* __restrict__ tptr, float* __restrict__ ws,
                  int ntiles) {
  const int lane = threadIdx.x & 63;
  const int wid  = blockIdx.x * 4 + (threadIdx.x >> 6);
  const int m = lane & 15;            // fragment row / C col
  const int h = lane >> 4;            // k-slice group / C row group
  const float inv_t = 1.0f / tptr[0];

  float loss = 0.0f;

  if (wid < ntiles) {
    const float4* pa = (const float4*)(ds + (size_t)wid * 4096);
    const float4* pb = (const float4*)(ss + (size_t)wid * 4096);
    const int base = m * 64 + h * 2;  // float4 idx: row m, k-offset h*8

    // ---- phase 1: issue all 32 independent dwordx4 loads ----
    float4 A[16], S[16];
#pragma unroll
    for (int kb = 0; kb < 8; ++kb) {
      A[2 * kb]     = pa[base + kb * 8];
      A[2 * kb + 1] = pa[base + kb * 8 + 1];
      S[2 * kb]     = pb[base + kb * 8];
      S[2 * kb + 1] = pb[base + kb * 8 + 1];
    }

    // ---- phase 2: ssq + cvt + MFMA against landed data ----
    f32x4 acc = {0.f, 0.f, 0.f, 0.f};
    float ssqA = 0.f, ssqS = 0.f;
#pragma unroll
    for (int kb = 0; kb < 8; ++kb) {
      float4 a0 = A[2 * kb], a1 = A[2 * kb + 1];
      float4 s0 = S[2 * kb], s1 = S[2 * kb + 1];

      ssqA += a0.x*a0.x + a0.y*a0.y + a0.z*a0.z + a0.w*a0.w
            + a1.x*a1.x + a1.y*a1.y + a1.z*a1.z + a1.w*a1.w;
      ssqS += s0.x*s0.x + s0.y*s0.y + s0.z*s0.z + s0.w*s0.w
            + s1.x*s1.x + s1.y*s1.y + s1.z*s1.z + s1.w*s1.w;

      acc = __builtin_amdgcn_mfma_f32_16x16x32_bf16(
          pack8(a0, a1), pack8(s0, s1), acc, 0, 0, 0);
    }

    // fold ssq over the 4 lanes sharing row m (bits 4,5)
    ssqA += __shfl_xor(ssqA, 16, 64);
    ssqA += __shfl_xor(ssqA, 32, 64);
    ssqS += __shfl_xor(ssqS, 16, 64);
    ssqS += __shfl_xor(ssqS, 32, 64);
    // C col = m, so ssqS is already this lane's col norm^2.
    float na0 = __shfl(ssqA, h * 4 + 0, 64);
    float na1 = __shfl(ssqA, h * 4 + 1, 64);
    float na2 = __shfl(ssqA, h * 4 + 2, 64);
    float na3 = __shfl(ssqA, h * 4 + 3, 64);

    float lg0 = acc[0] * rsqrtf(na0 * ssqS) * inv_t;
    float lg1 = acc[1] * rsqrtf(na1 * ssqS) * inv_t;
    float lg2 = acc[2] * rsqrtf(na2 * ssqS) * inv_t;
    float lg3 = acc[3] * rsqrtf(na3 * ssqS) * inv_t;

    float c = 0.0f;
#pragma unroll
    for (int r = 0; r < 4; ++r) {
      float lg = r == 0 ? lg0 : r == 1 ? lg1 : r == 2 ? lg2 : lg3;
      float mx = lg;
      mx = fmaxf(mx, __shfl_xor(mx, 1, 64));
      mx = fmaxf(mx, __shfl_xor(mx, 2, 64));
      mx = fmaxf(mx, __shfl_xor(mx, 4, 64));
      float e = __expf(lg - mx);
      e += __shfl_xor(e, 1, 64);
      e += __shfl_xor(e, 2, 64);
      e += __shfl_xor(e, 4, 64);
      float lse = mx + __logf(e);
      c += lse * 0.125f;                 // lse replicated across 8 col-lanes
      if (4 * h + r == m) c -= lg;       // diagonal positive
    }
    if ((m >= 8) == (h >= 2)) loss = c;  // same-batch quadrants only
  }

  // deterministic wave -> block reduction
#pragma unroll
  for (int o = 32; o >= 1; o >>= 1) loss += __shfl_xor(loss, o, 64);
  __shared__ float red[4];
  if (lane == 0) red[threadIdx.x >> 6] = loss;
  __syncthreads();
  if (threadIdx.x == 0)
    ws[blockIdx.x] = (red[0] + red[1]) + (red[2] + red[3]);
}

extern "C" __global__ __launch_bounds__(256)
void slot_ce_finish(const float* __restrict__ ws, float* __restrict__ out,
                    int nparts, float scale) {
  __shared__ float red[256];
  float s = 0.0f;
  for (int i = threadIdx.x; i < nparts; i += 256) s += ws[i];
  red[threadIdx.x] = s;
  __syncthreads();
  for (int o = 128; o >= 1; o >>= 1) {
    if ((int)threadIdx.x < o) red[threadIdx.x] += red[threadIdx.x + o];
    __syncthreads();
  }
  if (threadIdx.x == 0) out[0] = red[0] * scale;
}

extern "C" void kernel_launch(void* const* d_in, const int* in_sizes, int n_in,
                              void* d_out, int out_size, void* d_ws, size_t ws_size,
                              hipStream_t stream) {
  const float* ds   = (const float*)d_in[0];
  const float* ss   = (const float*)d_in[1];
  const float* tptr = (const float*)d_in[3];   // d_in[2] = labels (unused)
  float* out = (float*)d_out;
  float* ws  = (float*)d_ws;

  const int B      = in_sizes[0] / (8 * 256);  // 32768
  const int ntiles = B / 2;                    // 2 batches per wave-tile
  const int blocks = (ntiles + 3) / 4;         // 4 waves per block -> 4096

  slot_ce_mfma<<<blocks, 256, 0, stream>>>(ds, ss, tptr, ws, ntiles);
  const float scale = 1.0f / (8.0f * (float)B);
  slot_ce_finish<<<1, 256, 0, stream>>>(ws, out, blocks, scale);
}